// Round 6
// baseline (201.591 us; speedup 1.0000x reference)
//
#include <hip/hip_runtime.h>
#include <cstdint>
#include <cmath>

// RandomPhongShader: exact reproduction of JAX threefry-partitionable RNG +
// XLA CPU float32 numerics, fused shader.
//
// Round 6: instruction shaving on the round-5 structure.
//  - Heaviside decisions as pure integer compares: (bits>>9) vs precomputed
//    integer threshold T (from A&S erf), band +-6 units; flagged pixels redo
//    all 32 draws with the exact chain (single ballot).
//  - Argmax hot chain: v_log_f32 only (Taylor branch dropped -- v_log_f32 is
//    relatively accurate, abs err ~1e-9 near u=1), ln2 folded into ww-fma,
//    sqrt2*0.1 folded into score-fma, best/second margin check at end of the
//    9-draw scan instead of per-draw band (fewer ops AND fewer fallbacks).
//  - All f32 divisions replaced by f64 reciprocal-multiply (double-rounding
//    flip risk ~0.16 ulp-events x ~1e-5 decision impact: safe).
//  - No LDS (cold argmax redo unrolled, static indexing). No waves/EU cap
//    (round-2 spill lesson).
//
// Shapes: N=8,H=256,W=256,K=8, NB_SAMPLES=4. Pixels P = N*H*W = 524288.
// partitionable bits(i) = o0 ^ o1 of threefry2x32(key, (0, i))
// split(key(1)): kh = cipher((0,1),(0,0)), ka = cipher((0,1),(0,1))

#pragma clang fp contract(off)

#define NPIX 524288
#define STRIDE_H 4194304u
#define STRIDE_A 4718592u
#define BAND_A 5e-5f

__device__ __forceinline__ uint32_t rotl32(uint32_t v, int n) {
  return (v << n) | (v >> (32 - n));   // v_alignbit_b32
}

__device__ __forceinline__ void tf2x32(uint32_t k0, uint32_t k1,
                                       uint32_t c0, uint32_t c1,
                                       uint32_t& o0, uint32_t& o1) {
  const uint32_t k2 = k0 ^ k1 ^ 0x1BD11BDAu;
  uint32_t x0 = c0 + k0, x1 = c1 + k1;
#define TFR(r) { x0 += x1; x1 = rotl32(x1, r); x1 ^= x0; }
  TFR(13) TFR(15) TFR(26) TFR(6)
  x0 += k1;  x1 += k2 + 1u;
  TFR(17) TFR(29) TFR(16) TFR(24)
  x0 += k2;  x1 += k0 + 2u;
  TFR(13) TFR(15) TFR(26) TFR(6)
  x0 += k0;  x1 += k1 + 3u;
  TFR(17) TFR(29) TFR(16) TFR(24)
  x0 += k1;  x1 += k2 + 4u;
  TFR(13) TFR(15) TFR(26) TFR(6)
  x0 += k2;  x1 += k0 + 5u;
#undef TFR
  o0 = x0; o1 = x1;
}

// ---- exact path (cold): rounds-3..5-validated numerics ----
__device__ __forceinline__ double fast_log(double z) {
  uint64_t b = __double_as_longlong(z);
  int E = (int)(b >> 52) - 1023;
  double m = __longlong_as_double((b & 0x000FFFFFFFFFFFFFULL) |
                                  0x3FF0000000000000ULL);  // [1,2)
  bool c = m > 1.4142135623730951;
  m = c ? m * 0.5 : m;   // exact
  E = c ? E + 1 : E;
  double d = m + 1.0;
  double r = __builtin_amdgcn_rcp(d);
  r = fma(r, fma(-d, r, 1.0), r);
  r = fma(r, fma(-d, r, 1.0), r);              // ~2e-16 rel
  double s = (m - 1.0) * r;
  double u = s * s;
  double p = 1.0 / 19.0;
  p = fma(p, u, 1.0 / 17.0);
  p = fma(p, u, 1.0 / 15.0);
  p = fma(p, u, 1.0 / 13.0);
  p = fma(p, u, 1.0 / 11.0);
  p = fma(p, u, 1.0 / 9.0);
  p = fma(p, u, 1.0 / 7.0);
  p = fma(p, u, 1.0 / 5.0);
  p = fma(p, u, 1.0 / 3.0);
  p = fma(p, u, 1.0);
  double lm = (2.0 * s) * p;
  const double LN2_HI = 6.93147180369123816490e-01;
  const double LN2_LO = 1.90821492927058770002e-10;
  double e = (double)E;
  return fma(e, LN2_HI, fma(e, LN2_LO, lm));
}

__device__ __forceinline__ float normal_exact(uint32_t bits) {
  float f = __uint_as_float((bits >> 9) | 0x3f800000u) - 1.0f;  // exact
  const float lo = __uint_as_float(0xBF7FFFFFu);
  float v = __fadd_rn(__fmul_rn(f, 2.0f), lo);
  v = fmaxf(lo, v);
  float t = -__fmul_rn(v, v);
  float taylor = __fmul_rn(__fadd_rn(__fmul_rn(-0.5f, t), 1.0f), t);
  float lg = (float)fast_log((double)__fadd_rn(t, 1.0f));
  float l1p = (fabsf(t) < 1e-4f) ? taylor : lg;
  float w = -l1p;
  const bool lt = w < 5.0f;
  float ww = lt ? __fsub_rn(w, 2.5f) : __fsub_rn(__fsqrt_rn(w), 3.0f);
  float p  = lt ? 2.81022636e-08f : -0.000200214257f;
  p = __fadd_rn(lt ?  3.43273939e-07f :  0.000100950558f, __fmul_rn(p, ww));
  p = __fadd_rn(lt ? -3.5233877e-06f  :  0.00134934322f,  __fmul_rn(p, ww));
  p = __fadd_rn(lt ? -4.39150654e-06f : -0.00367342844f,  __fmul_rn(p, ww));
  p = __fadd_rn(lt ?  0.00021858087f  :  0.00573950773f,  __fmul_rn(p, ww));
  p = __fadd_rn(lt ? -0.00125372503f  : -0.0076224613f,   __fmul_rn(p, ww));
  p = __fadd_rn(lt ? -0.00417768164f  :  0.00943887047f,  __fmul_rn(p, ww));
  p = __fadd_rn(lt ?  0.246640727f    :  1.00167406f,     __fmul_rn(p, ww));
  p = __fadd_rn(lt ?  1.50140941f     :  2.83297682f,     __fmul_rn(p, ww));
  return __fmul_rn(__uint_as_float(0x3FB504F3u), __fmul_rn(p, v));
}

// ---- approx argmax score (hot). v kept bit-exact (tail slope amplifies v
// errors); log/poly approximated; |score_fast - score_exact| <~ 4e-6,
// BAND_A = 5e-5 gives >=12x margin.
__device__ __forceinline__ float score_fast(uint32_t bits, float zmj) {
  float f = __uint_as_float((bits >> 9) | 0x3f800000u) - 1.0f;  // exact
  const float lo = __uint_as_float(0xBF7FFFFFu);
  float v = fmaxf(lo, __fmaf_rn(f, 2.0f, lo));   // == RN(2f+lo), exact seq
  float t = -__fmul_rn(v, v);
  float u = __fadd_rn(t, 1.0f);
  float L = __builtin_amdgcn_logf(u);            // log2(u), <=0
  float ww = __fmaf_rn(-0.69314718f, L, -2.5f);  // w - 2.5
  float p = 2.81022636e-08f;
  p = __fmaf_rn(p, ww,  3.43273939e-07f);
  p = __fmaf_rn(p, ww, -3.5233877e-06f);
  p = __fmaf_rn(p, ww, -4.39150654e-06f);
  p = __fmaf_rn(p, ww,  0.00021858087f);
  p = __fmaf_rn(p, ww, -0.00125372503f);
  p = __fmaf_rn(p, ww, -0.00417768164f);
  p = __fmaf_rn(p, ww,  0.246640727f);
  p = __fmaf_rn(p, ww,  1.50140941f);
  if (__builtin_expect(__ballot(L <= -7.2134752f) != 0ull, 0)) {  // w>=5
    float w = __fmul_rn(-0.69314718f, L);
    float w2 = __builtin_amdgcn_sqrtf(w) - 3.0f;
    float q = -0.000200214257f;
    q = __fmaf_rn(q, w2,  0.000100950558f);
    q = __fmaf_rn(q, w2,  0.00134934322f);
    q = __fmaf_rn(q, w2, -0.00367342844f);
    q = __fmaf_rn(q, w2,  0.00573950773f);
    q = __fmaf_rn(q, w2, -0.0076224613f);
    q = __fmaf_rn(q, w2,  0.00943887047f);
    q = __fmaf_rn(q, w2,  1.00167406f);
    q = __fmaf_rn(q, w2,  2.83297682f);
    p = (L <= -7.2134752f) ? q : p;
  }
  // score = zm + 0.1*sqrt2*p*v (folded)
  return __fmaf_rn(__fmul_rn(p, v), 0.14142136f, zmj);
}

__global__ __launch_bounds__(256) void RandomPhongShader_kernel(
    const float* __restrict__ colors,   // (P,8,3)
    const float* __restrict__ dists,    // (P,8)
    const float* __restrict__ zbuf,     // (P,8)
    const int*   __restrict__ p2f,      // (P,8)
    const float* __restrict__ bg,       // (3,)
    float* __restrict__ out)            // (P,4)
{
  const int tid = threadIdx.x;
  const int P = blockIdx.x * 256 + tid;   // grid exact: 2048*256 == NPIX

  uint32_t kh0, kh1, ka0, ka1;            // constant-folded
  tf2x32(0u, 1u, 0u, 0u, kh0, kh1);
  tf2x32(0u, 1u, 0u, 1u, ka0, ka1);

  // hoisted loads
  float dk[8], zk[8];
  int mk[8];
  {
    const float4* d4 = reinterpret_cast<const float4*>(dists + (size_t)P * 8);
    float4 a = d4[0], b = d4[1];
    dk[0]=a.x; dk[1]=a.y; dk[2]=a.z; dk[3]=a.w; dk[4]=b.x; dk[5]=b.y; dk[6]=b.z; dk[7]=b.w;
    const float4* z4 = reinterpret_cast<const float4*>(zbuf + (size_t)P * 8);
    float4 c = z4[0], e = z4[1];
    zk[0]=c.x; zk[1]=c.y; zk[2]=c.z; zk[3]=c.w; zk[4]=e.x; zk[5]=e.y; zk[6]=e.z; zk[7]=e.w;
    const int4* m4 = reinterpret_cast<const int4*>(p2f + (size_t)P * 8);
    int4 f = m4[0], g = m4[1];
    mk[0]=f.x; mk[1]=f.y; mk[2]=f.z; mk[3]=f.w; mk[4]=g.x; mk[5]=g.y; mk[6]=g.z; mk[7]=g.w;
  }

  // ---- phase 0: integer thresholds. decision (bits>>9) >= T where
  // T = ceil((erf(10*d/sqrt2) + 0.99999994)*2^22). Band +-6 units covers
  // erf err (0.63u) + RN wiggle (<=2u) + conversion/ceil (<=2u).
  int Tm6[8];
  #pragma unroll
  for (int k = 0; k < 8; ++k) {
    float y = fabsf(dk[k]) * 7.0710678f;
    float tt = __builtin_amdgcn_rcpf(__fmaf_rn(0.3275911f, y, 1.0f));
    float ex = __builtin_amdgcn_exp2f(__fmul_rn(-1.4426951f, y * y));
    float pp = 1.061405429f;
    pp = __fmaf_rn(pp, tt, -1.453152027f);
    pp = __fmaf_rn(pp, tt,  1.421413741f);
    pp = __fmaf_rn(pp, tt, -0.284496736f);
    pp = __fmaf_rn(pp, tt,  0.254829592f);
    float er = __fmaf_rn(-pp * tt, ex, 1.0f);
    float vs = copysignf(er, dk[k]);
    int T = (int)ceilf(__fmul_rn(__fadd_rn(vs, 0.99999994f), 4194304.0f));
    Tm6[k] = T - 6;
  }

  // ---- phase 1: heaviside counts (integer hot path) ----
  uint32_t cntP = 0;          // 8 nibbles
  bool redoH = false;
  {
    uint32_t cH = (uint32_t)P * 8u;
    #pragma unroll 1
    for (int s = 0; s < 4; ++s) {
      #pragma unroll
      for (int k = 0; k < 8; ++k) {
        uint32_t o0, o1;
        tf2x32(kh0, kh1, 0u, cH + (uint32_t)k, o0, o1);
        int m = (int)((o0 ^ o1) >> 9);
        int sub = m - Tm6[k];
        cntP += (sub >= 6) ? (1u << (4 * k)) : 0u;
        redoH |= ((uint32_t)sub <= 12u);
      }
      cH += STRIDE_H;
    }
  }
  if (__builtin_expect(__ballot(redoH) != 0ull, 0)) {
    if (redoH) {   // exec-masked: redo all 32 draws exactly
      uint32_t c2 = 0;
      uint32_t cH = (uint32_t)P * 8u;
      #pragma unroll 1
      for (int s = 0; s < 4; ++s) {
        #pragma unroll 1
        for (int k = 0; k < 8; ++k) {
          uint32_t o0, o1;
          tf2x32(kh0, kh1, 0u, cH + (uint32_t)k, o0, o1);
          float nz = normal_exact(o0 ^ o1);
          float x = -dists[(size_t)P * 8 + k];
          c2 += (__fadd_rn(x, __fmul_rn(0.1f, nz)) >= 0.0f) ? (1u << (4 * k)) : 0u;
        }
        cH += STRIDE_H;
      }
      cntP = c2;
    }
  }

  // ---- phase 2: alpha, z_inv, z_map. Divisions via f64 recip-multiply
  // (double-rounding flip risk ~0.16 one-ulp events/run x ~1e-5 impact). ----
  const double D99 = 1.0 / 99.0;
  const double D01 = 1.0 / (double)0.1f;
  float zinv[8], zmax;
  #pragma unroll
  for (int k = 0; k < 8; ++k) {
    const float m = (mk[k] >= 0) ? 1.0f : 0.0f;
    float a = __fsub_rn(100.0f, zk[k]);
    float zi = __fmul_rn((float)((double)a * D99), m);
    zinv[k] = zi;
    zmax = (k == 0) ? zi : fmaxf(zmax, zi);
  }
  zmax = fmaxf(zmax, 1e-10f);

  const float lg0 = (float)-23.025850916589025;  // log(1e-10f)
  const float lg1 = (float)-1.3862943611198906;  // log(0.25)
  const float lg2 = (float)-0.6931471805599453;  // log(0.5)
  const float lg3 = (float)-0.2876820724517809;  // log(0.75)

  float alpha = 1.0f;
  float zm[9];
  #pragma unroll
  for (int k = 0; k < 8; ++k) {
    const int cntk = (int)((cntP >> (4 * k)) & 15u);
    const float m = (mk[k] >= 0) ? 1.0f : 0.0f;
    const float pm = __fmul_rn(__fmul_rn((float)cntk, 0.25f), m);
    alpha *= (1.0f - pm);  // exact
    const int i = (mk[k] >= 0) ? cntk : 0;
    const float lg = (i == 0) ? lg0 : (i == 1) ? lg1 : (i == 2) ? lg2
                   : (i == 3) ? lg3 : 0.0f;
    float sdf = __fsub_rn(zinv[k], zmax);
    zm[k] = __fadd_rn(lg, (float)((double)sdf * D01));
  }
  zm[8] = (float)((double)__fsub_rn(1e-10f, zmax) * D01);

  // ---- phase 3: random_argmax (approx scan + margin-at-end fallback) ----
  uint32_t amPack = 0;
  uint32_t cA = (uint32_t)P * 9u;
  #pragma unroll 1
  for (int s = 0; s < 4; ++s) {
    int am = 0;
    float best = -3.4e38f, second = -3.4e38f;
    #pragma unroll
    for (int j = 0; j < 9; ++j) {
      uint32_t o0, o1;
      tf2x32(ka0, ka1, 0u, cA + (uint32_t)j, o0, o1);
      float vv = score_fast(o0 ^ o1, zm[j]);
      bool g = vv > best;
      second = g ? best : fmaxf(second, vv);
      best = g ? vv : best;
      am = g ? j : am;
    }
    // winner robust iff top-2 gap exceeds 2*max approx error
    bool fl = __fsub_rn(best, second) < BAND_A;
    if (__builtin_expect(__ballot(fl) != 0ull, 0)) {
      if (fl) {   // exec-masked exact redo of this sample (static unroll)
        int ame = 0;
        float be = -3.4e38f;
        #pragma unroll
        for (int j = 0; j < 9; ++j) {
          uint32_t o0, o1;
          tf2x32(ka0, ka1, 0u, cA + (uint32_t)j, o0, o1);
          float nz = normal_exact(o0 ^ o1);
          float ve = __fadd_rn(zm[j], __fmul_rn(0.1f, nz));
          bool g = ve > be;
          be = g ? ve : be;
          ame = g ? j : ame;
        }
        am = ame;
      }
    }
    amPack += 1u << (3 * am);
    cA += STRIDE_A;
  }

  // ---- phase 4: epilogue ----
  float wgt[9];
  #pragma unroll
  for (int j = 0; j < 9; ++j)
    wgt[j] = __fmul_rn(0.25f, (float)((amPack >> (3 * j)) & 7u));  // exact

  float cc[24];
  {
    const float4* c4 = reinterpret_cast<const float4*>(colors + (size_t)P * 24);
    #pragma unroll
    for (int q = 0; q < 6; ++q) {
      float4 t = c4[q];
      cc[q*4+0]=t.x; cc[q*4+1]=t.y; cc[q*4+2]=t.z; cc[q*4+3]=t.w;
    }
  }
  float rgb[3];
  #pragma unroll
  for (int c = 0; c < 3; ++c) {
    float acc = 0.0f;
    #pragma unroll
    for (int k = 0; k < 8; ++k)
      acc = __fadd_rn(acc, __fmul_rn(wgt[k], cc[k * 3 + c]));
    rgb[c] = __fadd_rn(acc, __fmul_rn(wgt[8], bg[c]));
  }

  float4 o;
  o.x = rgb[0]; o.y = rgb[1]; o.z = rgb[2];
  o.w = __fsub_rn(1.0f, alpha);
  reinterpret_cast<float4*>(out)[P] = o;
}

extern "C" void kernel_launch(void* const* d_in, const int* in_sizes, int n_in,
                              void* d_out, int out_size, void* d_ws, size_t ws_size,
                              hipStream_t stream) {
  const float* colors = (const float*)d_in[0];
  const float* dists  = (const float*)d_in[1];
  const float* zbuf   = (const float*)d_in[2];
  const int*   p2f    = (const int*)d_in[3];
  const float* bg     = (const float*)d_in[4];
  float* out = (float*)d_out;
  dim3 grid(NPIX / 256), block(256);
  hipLaunchKernelGGL(RandomPhongShader_kernel, grid, block, 0, stream,
                     colors, dists, zbuf, p2f, bg, out);
}